// Round 3
// baseline (258.531 us; speedup 1.0000x reference)
//
#include <hip/hip_runtime.h>
#include <hip/hip_bf16.h>
#include <cstdint>
#include <cstddef>

typedef short bf16x8 __attribute__((ext_vector_type(8)));
typedef float f32x4 __attribute__((ext_vector_type(4)));
typedef unsigned short u16x8 __attribute__((ext_vector_type(8)));

#define DEV __device__ __forceinline__

DEV void gload16(const void* g, void* l) {
  __builtin_amdgcn_global_load_lds((const __attribute__((address_space(1))) void*)g,
                                   (__attribute__((address_space(3))) void*)l,
                                   16, 0, 0);
}

DEV unsigned short f2bf(float f) {
  __hip_bfloat16 h = __float2bfloat16(f);
  return *reinterpret_cast<unsigned short*>(&h);
}

// ---------------- convert x fp32 -> bf16 ----------------
__global__ __launch_bounds__(256) void k_cvt(const float* __restrict__ in,
                                             unsigned short* __restrict__ out,
                                             long n) {
  long i = ((long)blockIdx.x * 256 + threadIdx.x) * 8;
  if (i >= n) return;
  const float4* p = (const float4*)(in + i);
  float4 a = p[0], b = p[1];
  u16x8 r;
  r[0] = f2bf(a.x); r[1] = f2bf(a.y); r[2] = f2bf(a.z); r[3] = f2bf(a.w);
  r[4] = f2bf(b.x); r[5] = f2bf(b.y); r[6] = f2bf(b.z); r[7] = f2bf(b.w);
  *(u16x8*)(out + i) = r;
}

// ---------------- Wv_eff[k][d] = sum_h Wqkv[k][h][256+d]  (fp32) ----------------
__global__ __launch_bounds__(256) void k_wveff(const float* __restrict__ Wqkv,
                                               float* __restrict__ Wv) {
  int gid = blockIdx.x * 256 + threadIdx.x;  // 2048*128 = 262144
  int k = gid >> 7, d = gid & 127;
  const float* p = Wqkv + (size_t)k * 6144 + 256 + d;
  float s = 0.f;
#pragma unroll
  for (int h = 0; h < 16; ++h) s += p[h * 384];
  Wv[gid] = s;  // Wv[k*128 + d]
}

// ---------------- Wsum[d][m] = sum_h Wout[h][d][m]  (fp32) ----------------
__global__ __launch_bounds__(256) void k_wsum(const float* __restrict__ Wout,
                                              float* __restrict__ Ws) {
  int gid = blockIdx.x * 256 + threadIdx.x;  // 128*2048 = 262144
  int d = gid >> 11, m = gid & 2047;
  const float* p = Wout + (size_t)d * 2048 + m;
  float s = 0.f;
#pragma unroll
  for (int h = 0; h < 16; ++h) s += p[h * 262144];
  Ws[gid] = s;  // Ws[d*2048 + m]
}

// ---------------- beff[m] = bout[m] + sum_d (sum_h bqkv[h][256+d]) * Ws[d][m] ----------------
__global__ __launch_bounds__(256) void k_beff(const float* __restrict__ bqkv,
                                              const float* __restrict__ Ws,
                                              const float* __restrict__ bout,
                                              float* __restrict__ be) {
  __shared__ float bv[128];
  int t = threadIdx.x;
  if (t < 128) {
    float s = 0.f;
#pragma unroll
    for (int h = 0; h < 16; ++h) s += bqkv[h * 384 + 256 + t];
    bv[t] = s;
  }
  __syncthreads();
  int m = blockIdx.x * 256 + t;  // grid 8 -> 2048
  float s = bout[m];
  for (int d = 0; d < 128; ++d) s = fmaf(bv[d], Ws[(size_t)d * 2048 + m], s);
  be[m] = s;
}

// ---------------- Weff_t[n][k] = sum_d Wv[k][d] * Ws[d][n]  (fp32 acc -> bf16) ----------------
// grid 1024: tn = blockIdx.x & 31 (n-tile of 64), tk = blockIdx.x >> 5 (k-tile of 64)
__global__ __launch_bounds__(256) void k_weff(const float* __restrict__ Wv,
                                              const float* __restrict__ Ws,
                                              unsigned short* __restrict__ Wt) {
  __shared__ float wv_s[64][129];  // +1 pad: lane-stride 129 -> conflict-free
  __shared__ float ws_s[128][64];
  const int t = threadIdx.x;
  const int tn = blockIdx.x & 31, tk = blockIdx.x >> 5;
#pragma unroll
  for (int it = 0; it < 32; ++it) {
    int idx = it * 256 + t;  // 8192
    int kk = idx >> 7, dd = idx & 127;
    wv_s[kk][dd] = Wv[(size_t)(tk * 64 + kk) * 128 + dd];
    int d2 = idx >> 6, nn = idx & 63;
    ws_s[d2][nn] = Ws[(size_t)d2 * 2048 + tn * 64 + nn];
  }
  __syncthreads();
  const int kk = t & 63, ng = t >> 6;  // ng uniform per wave -> ws broadcast
  float acc[16];
#pragma unroll
  for (int j = 0; j < 16; ++j) acc[j] = 0.f;
  for (int d = 0; d < 128; ++d) {
    float wv = wv_s[kk][d];
    const float* wsrow = &ws_s[d][ng * 16];
#pragma unroll
    for (int j = 0; j < 16; ++j) acc[j] = fmaf(wv, wsrow[j], acc[j]);
  }
#pragma unroll
  for (int j = 0; j < 16; ++j) {
    int n = tn * 64 + ng * 16 + j;
    Wt[(size_t)n * 2048 + tk * 64 + kk] = f2bf(acc[j]);
  }
}

// ---------------- main GEMM: Y[16384][2048] = A[16384][2048](bf16) * Wt[n][k]^T + be ----------------
// m97 structure: 128x128 tile, 4 waves, 16x16x32 bf16 MFMA, global_load_lds width 16.
__global__ __launch_bounds__(256) void k_gemm(const unsigned short* __restrict__ A,
                                              const unsigned short* __restrict__ Bt,
                                              const float* __restrict__ bias,
                                              float* __restrict__ Y) {
  constexpr int KD = 2048;
  __shared__ unsigned short As[128 * 32];
  __shared__ unsigned short Bs[128 * 32];
  const int t = threadIdx.x, lane = t & 63, w = t >> 6;
  const int wr = w >> 1, wc = w & 1;
  const int l15 = lane & 15, l4 = lane >> 4;
  const int m0 = blockIdx.x * 128, n0 = blockIdx.y * 128;

  f32x4 acc[4][4];
#pragma unroll
  for (int i = 0; i < 4; ++i)
#pragma unroll
    for (int j = 0; j < 4; ++j)
#pragma unroll
      for (int r = 0; r < 4; ++r) acc[i][j][r] = 0.f;

  for (int kt = 0; kt < KD / 32; ++kt) {
    __syncthreads();
    const int k0 = kt * 32;
#pragma unroll
    for (int c = 0; c < 2; ++c) {
      int idx = c * 256 + t;
      const char* sa = (const char*)(A + (size_t)(m0 + (idx >> 2)) * KD + k0) + (idx & 3) * 16;
      gload16(sa, (void*)(As + c * 2048 + w * 512));
      const char* sb = (const char*)(Bt + (size_t)(n0 + (idx >> 2)) * KD + k0) + (idx & 3) * 16;
      gload16(sb, (void*)(Bs + c * 2048 + w * 512));
    }
    __syncthreads();
    bf16x8 af[4], bfr[4];
#pragma unroll
    for (int i = 0; i < 4; ++i) {
      af[i]  = *(const bf16x8*)(As + (wr * 64 + i * 16 + l15) * 32 + l4 * 8);
      bfr[i] = *(const bf16x8*)(Bs + (wc * 64 + i * 16 + l15) * 32 + l4 * 8);
    }
#pragma unroll
    for (int mi = 0; mi < 4; ++mi)
#pragma unroll
      for (int ni = 0; ni < 4; ++ni)
        acc[mi][ni] = __builtin_amdgcn_mfma_f32_16x16x32_bf16(af[mi], bfr[ni], acc[mi][ni], 0, 0, 0);
  }

#pragma unroll
  for (int ni = 0; ni < 4; ++ni) {
    const int n = n0 + wc * 64 + ni * 16 + l15;
    const float bv = bias[n];
#pragma unroll
    for (int mi = 0; mi < 4; ++mi) {
#pragma unroll
      for (int r = 0; r < 4; ++r) {
        int mg = m0 + wr * 64 + mi * 16 + l4 * 4 + r;
        Y[(size_t)mg * 2048 + n] = acc[mi][ni][r] + bv;
      }
    }
  }
}

extern "C" void kernel_launch(void* const* d_in, const int* in_sizes, int n_in,
                              void* d_out, int out_size, void* d_ws, size_t ws_size,
                              hipStream_t stream) {
  const float* x    = (const float*)d_in[0];
  const float* Wqkv = (const float*)d_in[1];
  const float* bqkv = (const float*)d_in[2];
  const float* Wout = (const float*)d_in[3];
  const float* bout = (const float*)d_in[4];
  float* y = (float*)d_out;

  char* ws = (char*)d_ws;
  unsigned short* xb   = (unsigned short*)(ws);                 // 67,108,864 B
  float*          Wv   = (float*)(ws + 67108864);               //  1,048,576 B
  float*          Wsm  = (float*)(ws + 68157440);               //  1,048,576 B
  float*          beff = (float*)(ws + 69206016);               //      8,192 B
  unsigned short* Wt   = (unsigned short*)(ws + 69214208);      //  8,388,608 B  (total ~78 MB)

  k_cvt<<<16384, 256, 0, stream>>>(x, xb, 33554432L);
  k_wveff<<<1024, 256, 0, stream>>>(Wqkv, Wv);
  k_wsum<<<1024, 256, 0, stream>>>(Wout, Wsm);
  k_beff<<<8, 256, 0, stream>>>(bqkv, Wsm, bout, beff);
  k_weff<<<1024, 256, 0, stream>>>(Wv, Wsm, Wt);
  k_gemm<<<dim3(128, 16), 256, 0, stream>>>(xb, Wt, beff, y);
}

// Round 4
// 216.663 us; speedup vs baseline: 1.1932x; 1.1932x over previous
//
#include <hip/hip_runtime.h>
#include <hip/hip_bf16.h>
#include <cstdint>
#include <cstddef>

typedef short bf16x8 __attribute__((ext_vector_type(8)));
typedef float f32x4 __attribute__((ext_vector_type(4)));
typedef unsigned short u16x8 __attribute__((ext_vector_type(8)));

#define DEV __device__ __forceinline__

DEV void gload16(const void* g, void* l) {
  __builtin_amdgcn_global_load_lds((const __attribute__((address_space(1))) void*)g,
                                   (__attribute__((address_space(3))) void*)l,
                                   16, 0, 0);
}

DEV unsigned short f2bf(float f) {
  __hip_bfloat16 h = __float2bfloat16(f);
  return *reinterpret_cast<unsigned short*>(&h);
}

// ---------------- convert x fp32 -> bf16 ----------------
__global__ __launch_bounds__(256) void k_cvt(const float* __restrict__ in,
                                             unsigned short* __restrict__ out,
                                             long n) {
  long i = ((long)blockIdx.x * 256 + threadIdx.x) * 8;
  if (i >= n) return;
  const float4* p = (const float4*)(in + i);
  float4 a = p[0], b = p[1];
  u16x8 r;
  r[0] = f2bf(a.x); r[1] = f2bf(a.y); r[2] = f2bf(a.z); r[3] = f2bf(a.w);
  r[4] = f2bf(b.x); r[5] = f2bf(b.y); r[6] = f2bf(b.z); r[7] = f2bf(b.w);
  *(u16x8*)(out + i) = r;
}

// ---------------- Wv_eff[k][d] = sum_h Wqkv[k][h][256+d]  (fp32) ----------------
__global__ __launch_bounds__(256) void k_wveff(const float* __restrict__ Wqkv,
                                               float* __restrict__ Wv) {
  int gid = blockIdx.x * 256 + threadIdx.x;  // 2048*128 = 262144
  int k = gid >> 7, d = gid & 127;
  const float* p = Wqkv + (size_t)k * 6144 + 256 + d;
  float s = 0.f;
#pragma unroll
  for (int h = 0; h < 16; ++h) s += p[h * 384];
  Wv[gid] = s;  // Wv[k*128 + d]
}

// ---------------- Wsum[d][m] = sum_h Wout[h][d][m]  (fp32) ----------------
__global__ __launch_bounds__(256) void k_wsum(const float* __restrict__ Wout,
                                              float* __restrict__ Ws) {
  int gid = blockIdx.x * 256 + threadIdx.x;  // 128*2048 = 262144
  int d = gid >> 11, m = gid & 2047;
  const float* p = Wout + (size_t)d * 2048 + m;
  float s = 0.f;
#pragma unroll
  for (int h = 0; h < 16; ++h) s += p[h * 262144];
  Ws[gid] = s;  // Ws[d*2048 + m]
}

// ---------------- beff[m] = bout[m] + sum_d (sum_h bqkv[h][256+d]) * Ws[d][m] ----------------
__global__ __launch_bounds__(256) void k_beff(const float* __restrict__ bqkv,
                                              const float* __restrict__ Ws,
                                              const float* __restrict__ bout,
                                              float* __restrict__ be) {
  __shared__ float bv[128];
  int t = threadIdx.x;
  if (t < 128) {
    float s = 0.f;
#pragma unroll
    for (int h = 0; h < 16; ++h) s += bqkv[h * 384 + 256 + t];
    bv[t] = s;
  }
  __syncthreads();
  int m = blockIdx.x * 256 + t;  // grid 8 -> 2048
  float s = bout[m];
  for (int d = 0; d < 128; ++d) s = fmaf(bv[d], Ws[(size_t)d * 2048 + m], s);
  be[m] = s;
}

// ---------------- Weff_t[n][k] = sum_d Wv[k][d] * Ws[d][n]  (fp32 acc -> bf16) ----------------
__global__ __launch_bounds__(256) void k_weff(const float* __restrict__ Wv,
                                              const float* __restrict__ Ws,
                                              unsigned short* __restrict__ Wt) {
  __shared__ float wv_s[64][129];
  __shared__ float ws_s[128][64];
  const int t = threadIdx.x;
  const int tn = blockIdx.x & 31, tk = blockIdx.x >> 5;
#pragma unroll
  for (int it = 0; it < 32; ++it) {
    int idx = it * 256 + t;  // 8192
    int kk = idx >> 7, dd = idx & 127;
    wv_s[kk][dd] = Wv[(size_t)(tk * 64 + kk) * 128 + dd];
    int d2 = idx >> 6, nn = idx & 63;
    ws_s[d2][nn] = Ws[(size_t)d2 * 2048 + tn * 64 + nn];
  }
  __syncthreads();
  const int kk = t & 63, ng = t >> 6;
  float acc[16];
#pragma unroll
  for (int j = 0; j < 16; ++j) acc[j] = 0.f;
  for (int d = 0; d < 128; ++d) {
    float wv = wv_s[kk][d];
    const float* wsrow = &ws_s[d][ng * 16];
#pragma unroll
    for (int j = 0; j < 16; ++j) acc[j] = fmaf(wv, wsrow[j], acc[j]);
  }
#pragma unroll
  for (int j = 0; j < 16; ++j) {
    int n = tn * 64 + ng * 16 + j;
    Wt[(size_t)n * 2048 + tk * 64 + kk] = f2bf(acc[j]);
  }
}

// ---------------- main GEMM: 256x256 tile, BK=64, 8 waves, phase-pipelined ----------------
// Y[16384][2048] = A(bf16) * Wt[n][k]^T + bias. grid 512 (1D): n-tile = bid&7 (XCD-local),
// m-tile = bid>>3. LDS 128 KiB dynamic: As[2]/Bs[2] of 256x64 bf16, XOR-swizzled
// (byte ^= (row&7)<<4) via pre-swizzled global source + swizzled ds_read (rule #21).
// Schedule: issue next tile's global_load_lds at iter top; 4 MFMA phases (16 MFMA each,
// setprio-wrapped, raw s_barrier rhythm, no drain); one __syncthreads per iter
// (its vmcnt(0) = "tile t+1 staged" condition). Correctness independent of phase barriers.
__global__ __launch_bounds__(512, 2) void k_gemm(const unsigned short* __restrict__ A,
                                                 const unsigned short* __restrict__ Bt,
                                                 const float* __restrict__ bias,
                                                 float* __restrict__ Y) {
  constexpr int KD = 2048;
  constexpr int NT = KD / 64;  // 32 K-tiles
  extern __shared__ char smem[];
  char* Asm = smem;              // 2 x 32768 B
  char* Bsm = smem + 65536;      // 2 x 32768 B
  const int t = threadIdx.x, lane = t & 63, w = t >> 6;
  const int wm = w >> 2, wn = w & 3;
  const int l15 = lane & 15, l4 = lane >> 4;
  const int bid = blockIdx.x;
  const int n0 = (bid & 7) * 256;
  const int m0 = (bid >> 3) * 256;

  // staging source (pre-swizzled): chunk c -> LDS rows c*64..c*64+63
  int srow[4], scol[4];
#pragma unroll
  for (int c = 0; c < 4; ++c) {
    srow[c] = (c * 512 + t) >> 3;
    scol[c] = ((t & 7) * 16) ^ ((srow[c] & 7) << 4);
  }
  const char* Ab = (const char*)A + (size_t)m0 * 4096;
  const char* Bb = (const char*)Bt + (size_t)n0 * 4096;

  f32x4 acc[8][4];
#pragma unroll
  for (int i = 0; i < 8; ++i)
#pragma unroll
    for (int j = 0; j < 4; ++j)
#pragma unroll
      for (int r = 0; r < 4; ++r) acc[i][j][r] = 0.f;

  // prologue: stage tile 0 into buf 0
#pragma unroll
  for (int c = 0; c < 4; ++c) {
    gload16(Ab + (size_t)srow[c] * 4096 + scol[c], Asm + c * 8192 + w * 1024);
    gload16(Bb + (size_t)srow[c] * 4096 + scol[c], Bsm + c * 8192 + w * 1024);
  }
  __syncthreads();

  int q = 0;
  for (int kt = 0; kt < NT; ++kt) {
    // issue next tile's staging into the other buffer (drained by iter-end syncthreads)
    if (kt + 1 < NT) {
      const size_t kb = (size_t)(kt + 1) * 128;
      char* Ad = Asm + (q ^ 1) * 32768;
      char* Bd = Bsm + (q ^ 1) * 32768;
#pragma unroll
      for (int c = 0; c < 4; ++c) {
        gload16(Ab + (size_t)srow[c] * 4096 + kb + scol[c], Ad + c * 8192 + w * 1024);
        gload16(Bb + (size_t)srow[c] * 4096 + kb + scol[c], Bd + c * 8192 + w * 1024);
      }
    }
    const char* Ar = Asm + q * 32768;
    const char* Br = Bsm + q * 32768;

    bf16x8 bfr[4][2];
#pragma unroll
    for (int ph = 0; ph < 4; ++ph) {
      if (ph == 0) {
#pragma unroll
        for (int ni = 0; ni < 4; ++ni)
#pragma unroll
          for (int ks = 0; ks < 2; ++ks) {
            int row = wn * 64 + ni * 16 + l15;
            int colb = (ks * 64 + l4 * 16) ^ ((row & 7) << 4);
            bfr[ni][ks] = *(const bf16x8*)(Br + row * 128 + colb);
          }
      }
      bf16x8 af[2][2];
#pragma unroll
      for (int j = 0; j < 2; ++j)
#pragma unroll
        for (int ks = 0; ks < 2; ++ks) {
          int row = wm * 128 + (ph * 2 + j) * 16 + l15;
          int colb = (ks * 64 + l4 * 16) ^ ((row & 7) << 4);
          af[j][ks] = *(const bf16x8*)(Ar + row * 128 + colb);
        }
      __builtin_amdgcn_s_setprio(1);
#pragma unroll
      for (int j = 0; j < 2; ++j)
#pragma unroll
        for (int ni = 0; ni < 4; ++ni)
#pragma unroll
          for (int ks = 0; ks < 2; ++ks)
            acc[ph * 2 + j][ni] =
                __builtin_amdgcn_mfma_f32_16x16x32_bf16(af[j][ks], bfr[ni][ks],
                                                        acc[ph * 2 + j][ni], 0, 0, 0);
      __builtin_amdgcn_s_setprio(0);
      __builtin_amdgcn_s_barrier();  // phase rhythm only — no vmcnt drain
    }
    __syncthreads();  // drains vmcnt(0): next tile resident; all reads of buf q done
    q ^= 1;
  }

  // epilogue
#pragma unroll
  for (int ni = 0; ni < 4; ++ni) {
    const int n = n0 + wn * 64 + ni * 16 + l15;
    const float bv = bias[n];
#pragma unroll
    for (int mi = 0; mi < 8; ++mi) {
#pragma unroll
      for (int r = 0; r < 4; ++r) {
        int mg = m0 + wm * 128 + mi * 16 + l4 * 4 + r;
        Y[(size_t)mg * 2048 + n] = acc[mi][ni][r] + bv;
      }
    }
  }
}

extern "C" void kernel_launch(void* const* d_in, const int* in_sizes, int n_in,
                              void* d_out, int out_size, void* d_ws, size_t ws_size,
                              hipStream_t stream) {
  const float* x    = (const float*)d_in[0];
  const float* Wqkv = (const float*)d_in[1];
  const float* bqkv = (const float*)d_in[2];
  const float* Wout = (const float*)d_in[3];
  const float* bout = (const float*)d_in[4];
  float* y = (float*)d_out;

  char* ws = (char*)d_ws;
  unsigned short* xb   = (unsigned short*)(ws);                 // 67,108,864 B
  float*          Wv   = (float*)(ws + 67108864);               //  1,048,576 B
  float*          Wsm  = (float*)(ws + 68157440);               //  1,048,576 B
  float*          beff = (float*)(ws + 69206016);               //      8,192 B
  unsigned short* Wt   = (unsigned short*)(ws + 69214208);      //  8,388,608 B  (total ~78 MB)

  k_cvt<<<16384, 256, 0, stream>>>(x, xb, 33554432L);
  k_wveff<<<1024, 256, 0, stream>>>(Wqkv, Wv);
  k_wsum<<<1024, 256, 0, stream>>>(Wout, Wsm);
  k_beff<<<8, 256, 0, stream>>>(bqkv, Wsm, bout, beff);
  k_weff<<<1024, 256, 0, stream>>>(Wv, Wsm, Wt);
  k_gemm<<<512, 512, 131072, stream>>>(xb, Wt, beff, y);
}

// Round 5
// 213.278 us; speedup vs baseline: 1.2122x; 1.0159x over previous
//
#include <hip/hip_runtime.h>
#include <hip/hip_bf16.h>
#include <cstdint>
#include <cstddef>

typedef short bf16x8 __attribute__((ext_vector_type(8)));
typedef float f32x4 __attribute__((ext_vector_type(4)));
typedef unsigned short u16x8 __attribute__((ext_vector_type(8)));

#define DEV __device__ __forceinline__

DEV void gload16(const void* g, void* l) {
  __builtin_amdgcn_global_load_lds((const __attribute__((address_space(1))) void*)g,
                                   (__attribute__((address_space(3))) void*)l,
                                   16, 0, 0);
}

DEV unsigned short f2bf(float f) {
  __hip_bfloat16 h = __float2bfloat16(f);
  return *reinterpret_cast<unsigned short*>(&h);
}

// ---------------- convert x fp32 -> bf16 (NT loads: x is read exactly once) ----------------
__global__ __launch_bounds__(256) void k_cvt(const float* __restrict__ in,
                                             unsigned short* __restrict__ out,
                                             long n) {
  long i = ((long)blockIdx.x * 256 + threadIdx.x) * 8;
  if (i >= n) return;
  const f32x4* p = (const f32x4*)(in + i);
  f32x4 a = __builtin_nontemporal_load(p);
  f32x4 b = __builtin_nontemporal_load(p + 1);
  u16x8 r;
  r[0] = f2bf(a[0]); r[1] = f2bf(a[1]); r[2] = f2bf(a[2]); r[3] = f2bf(a[3]);
  r[4] = f2bf(b[0]); r[5] = f2bf(b[1]); r[6] = f2bf(b[2]); r[7] = f2bf(b[3]);
  *(u16x8*)(out + i) = r;  // xb is re-read by k_gemm: keep cached
}

// ---------------- Wv_eff[k][d] = sum_h Wqkv[k][h][256+d]  (fp32) ----------------
__global__ __launch_bounds__(256) void k_wveff(const float* __restrict__ Wqkv,
                                               float* __restrict__ Wv) {
  int gid = blockIdx.x * 256 + threadIdx.x;  // 2048*128 = 262144
  int k = gid >> 7, d = gid & 127;
  const float* p = Wqkv + (size_t)k * 6144 + 256 + d;
  float s = 0.f;
#pragma unroll
  for (int h = 0; h < 16; ++h) s += __builtin_nontemporal_load(p + h * 384);
  Wv[gid] = s;  // Wv[k*128 + d]
}

// ---------------- Wsum[d][m] = sum_h Wout[h][d][m]  (fp32; NT: Wout read once) ----------------
__global__ __launch_bounds__(256) void k_wsum(const float* __restrict__ Wout,
                                              float* __restrict__ Ws) {
  int gid = blockIdx.x * 256 + threadIdx.x;  // 128*2048 = 262144
  int d = gid >> 11, m = gid & 2047;
  const float* p = Wout + (size_t)d * 2048 + m;
  float s = 0.f;
#pragma unroll
  for (int h = 0; h < 16; ++h) s += __builtin_nontemporal_load(p + h * 262144);
  Ws[gid] = s;  // Ws[d*2048 + m]
}

// ---------------- beff[m] = bout[m] + sum_d (sum_h bqkv[h][256+d]) * Ws[d][m] ----------------
__global__ __launch_bounds__(256) void k_beff(const float* __restrict__ bqkv,
                                              const float* __restrict__ Ws,
                                              const float* __restrict__ bout,
                                              float* __restrict__ be) {
  __shared__ float bv[128];
  int t = threadIdx.x;
  if (t < 128) {
    float s = 0.f;
#pragma unroll
    for (int h = 0; h < 16; ++h) s += bqkv[h * 384 + 256 + t];
    bv[t] = s;
  }
  __syncthreads();
  int m = blockIdx.x * 256 + t;  // grid 8 -> 2048
  float s = bout[m];
  for (int d = 0; d < 128; ++d) s = fmaf(bv[d], Ws[(size_t)d * 2048 + m], s);
  be[m] = s;
}

// ---------------- Weff_t[n][k] = sum_d Wv[k][d] * Ws[d][n]  (fp32 acc -> bf16) ----------------
__global__ __launch_bounds__(256) void k_weff(const float* __restrict__ Wv,
                                              const float* __restrict__ Ws,
                                              unsigned short* __restrict__ Wt) {
  __shared__ float wv_s[64][129];
  __shared__ float ws_s[128][64];
  const int t = threadIdx.x;
  const int tn = blockIdx.x & 31, tk = blockIdx.x >> 5;
#pragma unroll
  for (int it = 0; it < 32; ++it) {
    int idx = it * 256 + t;  // 8192
    int kk = idx >> 7, dd = idx & 127;
    wv_s[kk][dd] = Wv[(size_t)(tk * 64 + kk) * 128 + dd];
    int d2 = idx >> 6, nn = idx & 63;
    ws_s[d2][nn] = Ws[(size_t)d2 * 2048 + tn * 64 + nn];
  }
  __syncthreads();
  const int kk = t & 63, ng = t >> 6;
  float acc[16];
#pragma unroll
  for (int j = 0; j < 16; ++j) acc[j] = 0.f;
  for (int d = 0; d < 128; ++d) {
    float wv = wv_s[kk][d];
    const float* wsrow = &ws_s[d][ng * 16];
#pragma unroll
    for (int j = 0; j < 16; ++j) acc[j] = fmaf(wv, wsrow[j], acc[j]);
  }
#pragma unroll
  for (int j = 0; j < 16; ++j) {
    int n = tn * 64 + ng * 16 + j;
    Wt[(size_t)n * 2048 + tk * 64 + kk] = f2bf(acc[j]);
  }
}

// ---------------- main GEMM: 256x256 tile, BK=64, 8 waves, phase-pipelined ----------------
// Y[16384][2048] = A(bf16) * Wt[n][k]^T + bias. grid 512 (1D): n-tile = bid&7 (XCD-local),
// m-tile = bid>>3. LDS 128 KiB dynamic, XOR-swizzled both-sides (rule #21).
// y stores are NON-TEMPORAL: y is never re-read; without nt it write-allocates and
// thrashes A out of L2/L3 (round-4 FETCH_SIZE showed ~4x A overfetch).
__global__ __launch_bounds__(512, 2) void k_gemm(const unsigned short* __restrict__ A,
                                                 const unsigned short* __restrict__ Bt,
                                                 const float* __restrict__ bias,
                                                 float* __restrict__ Y) {
  constexpr int KD = 2048;
  constexpr int NT = KD / 64;  // 32 K-tiles
  extern __shared__ char smem[];
  char* Asm = smem;              // 2 x 32768 B
  char* Bsm = smem + 65536;      // 2 x 32768 B
  const int t = threadIdx.x, lane = t & 63, w = t >> 6;
  const int wm = w >> 2, wn = w & 3;
  const int l15 = lane & 15, l4 = lane >> 4;
  const int bid = blockIdx.x;
  const int n0 = (bid & 7) * 256;
  const int m0 = (bid >> 3) * 256;

  // staging source (pre-swizzled): chunk c -> LDS rows c*64..c*64+63
  int srow[4], scol[4];
#pragma unroll
  for (int c = 0; c < 4; ++c) {
    srow[c] = (c * 512 + t) >> 3;
    scol[c] = ((t & 7) * 16) ^ ((srow[c] & 7) << 4);
  }
  const char* Ab = (const char*)A + (size_t)m0 * 4096;
  const char* Bb = (const char*)Bt + (size_t)n0 * 4096;

  f32x4 acc[8][4];
#pragma unroll
  for (int i = 0; i < 8; ++i)
#pragma unroll
    for (int j = 0; j < 4; ++j)
#pragma unroll
      for (int r = 0; r < 4; ++r) acc[i][j][r] = 0.f;

  // prologue: stage tile 0 into buf 0
#pragma unroll
  for (int c = 0; c < 4; ++c) {
    gload16(Ab + (size_t)srow[c] * 4096 + scol[c], Asm + c * 8192 + w * 1024);
    gload16(Bb + (size_t)srow[c] * 4096 + scol[c], Bsm + c * 8192 + w * 1024);
  }
  __syncthreads();

  int q = 0;
  for (int kt = 0; kt < NT; ++kt) {
    // issue next tile's staging into the other buffer (drained by iter-end syncthreads)
    if (kt + 1 < NT) {
      const size_t kb = (size_t)(kt + 1) * 128;
      char* Ad = Asm + (q ^ 1) * 32768;
      char* Bd = Bsm + (q ^ 1) * 32768;
#pragma unroll
      for (int c = 0; c < 4; ++c) {
        gload16(Ab + (size_t)srow[c] * 4096 + kb + scol[c], Ad + c * 8192 + w * 1024);
        gload16(Bb + (size_t)srow[c] * 4096 + kb + scol[c], Bd + c * 8192 + w * 1024);
      }
    }
    const char* Ar = Asm + q * 32768;
    const char* Br = Bsm + q * 32768;

    bf16x8 bfr[4][2];
#pragma unroll
    for (int ph = 0; ph < 4; ++ph) {
      if (ph == 0) {
#pragma unroll
        for (int ni = 0; ni < 4; ++ni)
#pragma unroll
          for (int ks = 0; ks < 2; ++ks) {
            int row = wn * 64 + ni * 16 + l15;
            int colb = (ks * 64 + l4 * 16) ^ ((row & 7) << 4);
            bfr[ni][ks] = *(const bf16x8*)(Br + row * 128 + colb);
          }
      }
      bf16x8 af[2][2];
#pragma unroll
      for (int j = 0; j < 2; ++j)
#pragma unroll
        for (int ks = 0; ks < 2; ++ks) {
          int row = wm * 128 + (ph * 2 + j) * 16 + l15;
          int colb = (ks * 64 + l4 * 16) ^ ((row & 7) << 4);
          af[j][ks] = *(const bf16x8*)(Ar + row * 128 + colb);
        }
      __builtin_amdgcn_s_setprio(1);
#pragma unroll
      for (int j = 0; j < 2; ++j)
#pragma unroll
        for (int ni = 0; ni < 4; ++ni)
#pragma unroll
          for (int ks = 0; ks < 2; ++ks)
            acc[ph * 2 + j][ni] =
                __builtin_amdgcn_mfma_f32_16x16x32_bf16(af[j][ks], bfr[ni][ks],
                                                        acc[ph * 2 + j][ni], 0, 0, 0);
      __builtin_amdgcn_s_setprio(0);
      __builtin_amdgcn_s_barrier();  // phase rhythm only — no vmcnt drain
    }
    __syncthreads();  // drains vmcnt(0): next tile resident; all reads of buf q done
    q ^= 1;
  }

  // epilogue: non-temporal y stores (never re-read; keep A/B hot in cache)
#pragma unroll
  for (int ni = 0; ni < 4; ++ni) {
    const int n = n0 + wn * 64 + ni * 16 + l15;
    const float bv = bias[n];
#pragma unroll
    for (int mi = 0; mi < 8; ++mi) {
#pragma unroll
      for (int r = 0; r < 4; ++r) {
        int mg = m0 + wm * 128 + mi * 16 + l4 * 4 + r;
        __builtin_nontemporal_store(acc[mi][ni][r] + bv, &Y[(size_t)mg * 2048 + n]);
      }
    }
  }
}

extern "C" void kernel_launch(void* const* d_in, const int* in_sizes, int n_in,
                              void* d_out, int out_size, void* d_ws, size_t ws_size,
                              hipStream_t stream) {
  const float* x    = (const float*)d_in[0];
  const float* Wqkv = (const float*)d_in[1];
  const float* bqkv = (const float*)d_in[2];
  const float* Wout = (const float*)d_in[3];
  const float* bout = (const float*)d_in[4];
  float* y = (float*)d_out;

  char* ws = (char*)d_ws;
  unsigned short* xb   = (unsigned short*)(ws);                 // 67,108,864 B
  float*          Wv   = (float*)(ws + 67108864);               //  1,048,576 B
  float*          Wsm  = (float*)(ws + 68157440);               //  1,048,576 B
  float*          beff = (float*)(ws + 69206016);               //      8,192 B
  unsigned short* Wt   = (unsigned short*)(ws + 69214208);      //  8,388,608 B  (total ~78 MB)

  k_cvt<<<16384, 256, 0, stream>>>(x, xb, 33554432L);
  k_wveff<<<1024, 256, 0, stream>>>(Wqkv, Wv);
  k_wsum<<<1024, 256, 0, stream>>>(Wout, Wsm);
  k_beff<<<8, 256, 0, stream>>>(bqkv, Wsm, bout, beff);
  k_weff<<<1024, 256, 0, stream>>>(Wv, Wsm, Wt);
  k_gemm<<<512, 512, 131072, stream>>>(xb, Wt, beff, y);
}

// Round 6
// 201.328 us; speedup vs baseline: 1.2841x; 1.0594x over previous
//
#include <hip/hip_runtime.h>
#include <hip/hip_bf16.h>
#include <cstdint>
#include <cstddef>

typedef short bf16x8 __attribute__((ext_vector_type(8)));
typedef float f32x4 __attribute__((ext_vector_type(4)));
typedef unsigned short u16x8 __attribute__((ext_vector_type(8)));

#define DEV __device__ __forceinline__

DEV void gload16(const void* g, void* l) {
  __builtin_amdgcn_global_load_lds((const __attribute__((address_space(1))) void*)g,
                                   (__attribute__((address_space(3))) void*)l,
                                   16, 0, 0);
}

DEV unsigned short f2bf(float f) {
  __hip_bfloat16 h = __float2bfloat16(f);
  return *reinterpret_cast<unsigned short*>(&h);
}

// ---------------- convert x fp32 -> bf16 (NT loads: x is read exactly once) ----------------
__global__ __launch_bounds__(256) void k_cvt(const float* __restrict__ in,
                                             unsigned short* __restrict__ out,
                                             long n) {
  long i = ((long)blockIdx.x * 256 + threadIdx.x) * 8;
  if (i >= n) return;
  const f32x4* p = (const f32x4*)(in + i);
  f32x4 a = __builtin_nontemporal_load(p);
  f32x4 b = __builtin_nontemporal_load(p + 1);
  u16x8 r;
  r[0] = f2bf(a[0]); r[1] = f2bf(a[1]); r[2] = f2bf(a[2]); r[3] = f2bf(a[3]);
  r[4] = f2bf(b[0]); r[5] = f2bf(b[1]); r[6] = f2bf(b[2]); r[7] = f2bf(b[3]);
  *(u16x8*)(out + i) = r;  // xb is re-read by k_gemm: keep cached
}

// ---------------- Wv_eff[k][d] = sum_h Wqkv[k][h][256+d]  (fp32) ----------------
__global__ __launch_bounds__(256) void k_wveff(const float* __restrict__ Wqkv,
                                               float* __restrict__ Wv) {
  int gid = blockIdx.x * 256 + threadIdx.x;  // 2048*128 = 262144
  int k = gid >> 7, d = gid & 127;
  const float* p = Wqkv + (size_t)k * 6144 + 256 + d;
  float s = 0.f;
#pragma unroll
  for (int h = 0; h < 16; ++h) s += __builtin_nontemporal_load(p + h * 384);
  Wv[gid] = s;  // Wv[k*128 + d]
}

// ---------------- Wsum[d][m] = sum_h Wout[h][d][m]  (fp32; NT: Wout read once) ----------------
__global__ __launch_bounds__(256) void k_wsum(const float* __restrict__ Wout,
                                              float* __restrict__ Ws) {
  int gid = blockIdx.x * 256 + threadIdx.x;  // 128*2048 = 262144
  int d = gid >> 11, m = gid & 2047;
  const float* p = Wout + (size_t)d * 2048 + m;
  float s = 0.f;
#pragma unroll
  for (int h = 0; h < 16; ++h) s += __builtin_nontemporal_load(p + h * 262144);
  Ws[gid] = s;  // Ws[d*2048 + m]
}

// ---------------- beff[m] = bout[m] + sum_d (sum_h bqkv[h][256+d]) * Ws[d][m] ----------------
__global__ __launch_bounds__(256) void k_beff(const float* __restrict__ bqkv,
                                              const float* __restrict__ Ws,
                                              const float* __restrict__ bout,
                                              float* __restrict__ be) {
  __shared__ float bv[128];
  int t = threadIdx.x;
  if (t < 128) {
    float s = 0.f;
#pragma unroll
    for (int h = 0; h < 16; ++h) s += bqkv[h * 384 + 256 + t];
    bv[t] = s;
  }
  __syncthreads();
  int m = blockIdx.x * 256 + t;  // grid 8 -> 2048
  float s = bout[m];
  for (int d = 0; d < 128; ++d) s = fmaf(bv[d], Ws[(size_t)d * 2048 + m], s);
  be[m] = s;
}

// ---------------- Weff_t[n][k] = sum_d Wv[k][d] * Ws[d][n]  (fp32 acc -> bf16) ----------------
__global__ __launch_bounds__(256) void k_weff(const float* __restrict__ Wv,
                                              const float* __restrict__ Ws,
                                              unsigned short* __restrict__ Wt) {
  __shared__ float wv_s[64][129];
  __shared__ float ws_s[128][64];
  const int t = threadIdx.x;
  const int tn = blockIdx.x & 31, tk = blockIdx.x >> 5;
#pragma unroll
  for (int it = 0; it < 32; ++it) {
    int idx = it * 256 + t;  // 8192
    int kk = idx >> 7, dd = idx & 127;
    wv_s[kk][dd] = Wv[(size_t)(tk * 64 + kk) * 128 + dd];
    int d2 = idx >> 6, nn = idx & 63;
    ws_s[d2][nn] = Ws[(size_t)d2 * 2048 + tn * 64 + nn];
  }
  __syncthreads();
  const int kk = t & 63, ng = t >> 6;
  float acc[16];
#pragma unroll
  for (int j = 0; j < 16; ++j) acc[j] = 0.f;
  for (int d = 0; d < 128; ++d) {
    float wv = wv_s[kk][d];
    const float* wsrow = &ws_s[d][ng * 16];
#pragma unroll
    for (int j = 0; j < 16; ++j) acc[j] = fmaf(wv, wsrow[j], acc[j]);
  }
#pragma unroll
  for (int j = 0; j < 16; ++j) {
    int n = tn * 64 + ng * 16 + j;
    Wt[(size_t)n * 2048 + tk * 64 + kk] = f2bf(acc[j]);
  }
}

// ---------------- main GEMM: 256x256 tile, BK=64, 8 waves, phase-pipelined ----------------
// Y[16384][2048] = A(bf16) * Wt[n][k]^T + bias.
// XCD-locality remap (minimize per-XCD A+B footprint: m_x = n_x = 8):
//   XCD x = bid&7 owns m-tiles 8x..8x+7 across ALL n-tiles. Per co-resident
//   round (32 blocks/XCD, 1 block/CU) it runs 4 m-tiles x 8 n-tiles, so each
//   A-line is shared by 8 concurrent blocks through the XCD's L2 instead of
//   being re-fetched by up to 8 XCDs (round-4/5 FETCH showed 4x A over-fetch,
//   = the ~3100 cyc/iter stall). B (8 MB) stays L3-resident.
// LDS 128 KiB dynamic, XOR-swizzled both-sides (rule #21).
__global__ __launch_bounds__(512, 2) void k_gemm(const unsigned short* __restrict__ A,
                                                 const unsigned short* __restrict__ Bt,
                                                 const float* __restrict__ bias,
                                                 float* __restrict__ Y) {
  constexpr int KD = 2048;
  constexpr int NT = KD / 64;  // 32 K-tiles
  extern __shared__ char smem[];
  char* Asm = smem;              // 2 x 32768 B
  char* Bsm = smem + 65536;      // 2 x 32768 B
  const int t = threadIdx.x, lane = t & 63, w = t >> 6;
  const int wm = w >> 2, wn = w & 3;
  const int l15 = lane & 15, l4 = lane >> 4;
  const int bid = blockIdx.x;
  const int xcd = bid & 7;            // dispatch round-robins blocks over XCDs
  const int j = bid >> 3;             // per-XCD sequence 0..63
  const int rnd = j >> 5;             // co-resident round 0/1
  const int mt = xcd * 8 + rnd * 4 + ((j & 31) >> 3);
  const int ntile = j & 7;
  const int m0 = mt * 256, n0 = ntile * 256;

  // staging source (pre-swizzled): chunk c -> LDS rows c*64..c*64+63
  int srow[4], scol[4];
#pragma unroll
  for (int c = 0; c < 4; ++c) {
    srow[c] = (c * 512 + t) >> 3;
    scol[c] = ((t & 7) * 16) ^ ((srow[c] & 7) << 4);
  }
  const char* Ab = (const char*)A + (size_t)m0 * 4096;
  const char* Bb = (const char*)Bt + (size_t)n0 * 4096;

  f32x4 acc[8][4];
#pragma unroll
  for (int i = 0; i < 8; ++i)
#pragma unroll
    for (int j2 = 0; j2 < 4; ++j2)
#pragma unroll
      for (int r = 0; r < 4; ++r) acc[i][j2][r] = 0.f;

  // prologue: stage tile 0 into buf 0
#pragma unroll
  for (int c = 0; c < 4; ++c) {
    gload16(Ab + (size_t)srow[c] * 4096 + scol[c], Asm + c * 8192 + w * 1024);
    gload16(Bb + (size_t)srow[c] * 4096 + scol[c], Bsm + c * 8192 + w * 1024);
  }
  __syncthreads();

  int q = 0;
  for (int kt = 0; kt < NT; ++kt) {
    // issue next tile's staging into the other buffer (drained by iter-end syncthreads)
    if (kt + 1 < NT) {
      const size_t kb = (size_t)(kt + 1) * 128;
      char* Ad = Asm + (q ^ 1) * 32768;
      char* Bd = Bsm + (q ^ 1) * 32768;
#pragma unroll
      for (int c = 0; c < 4; ++c) {
        gload16(Ab + (size_t)srow[c] * 4096 + kb + scol[c], Ad + c * 8192 + w * 1024);
        gload16(Bb + (size_t)srow[c] * 4096 + kb + scol[c], Bd + c * 8192 + w * 1024);
      }
    }
    const char* Ar = Asm + q * 32768;
    const char* Br = Bsm + q * 32768;

    bf16x8 bfr[4][2];
#pragma unroll
    for (int ph = 0; ph < 4; ++ph) {
      if (ph == 0) {
#pragma unroll
        for (int ni = 0; ni < 4; ++ni)
#pragma unroll
          for (int ks = 0; ks < 2; ++ks) {
            int row = wn * 64 + ni * 16 + l15;
            int colb = (ks * 64 + l4 * 16) ^ ((row & 7) << 4);
            bfr[ni][ks] = *(const bf16x8*)(Br + row * 128 + colb);
          }
      }
      bf16x8 af[2][2];
#pragma unroll
      for (int jj = 0; jj < 2; ++jj)
#pragma unroll
        for (int ks = 0; ks < 2; ++ks) {
          int row = wm * 128 + (ph * 2 + jj) * 16 + l15;
          int colb = (ks * 64 + l4 * 16) ^ ((row & 7) << 4);
          af[jj][ks] = *(const bf16x8*)(Ar + row * 128 + colb);
        }
      __builtin_amdgcn_s_setprio(1);
#pragma unroll
      for (int jj = 0; jj < 2; ++jj)
#pragma unroll
        for (int ni = 0; ni < 4; ++ni)
#pragma unroll
          for (int ks = 0; ks < 2; ++ks)
            acc[ph * 2 + jj][ni] =
                __builtin_amdgcn_mfma_f32_16x16x32_bf16(af[jj][ks], bfr[ni][ks],
                                                        acc[ph * 2 + jj][ni], 0, 0, 0);
      __builtin_amdgcn_s_setprio(0);
      __builtin_amdgcn_s_barrier();  // phase rhythm only — no vmcnt drain
    }
    __syncthreads();  // drains vmcnt(0): next tile resident; all reads of buf q done
    q ^= 1;
  }

  // epilogue (plain stores; NT variant regressed in round 5)
#pragma unroll
  for (int ni = 0; ni < 4; ++ni) {
    const int n = n0 + wn * 64 + ni * 16 + l15;
    const float bv = bias[n];
#pragma unroll
    for (int mi = 0; mi < 8; ++mi) {
#pragma unroll
      for (int r = 0; r < 4; ++r) {
        int mg = m0 + wm * 128 + mi * 16 + l4 * 4 + r;
        Y[(size_t)mg * 2048 + n] = acc[mi][ni][r] + bv;
      }
    }
  }
}

extern "C" void kernel_launch(void* const* d_in, const int* in_sizes, int n_in,
                              void* d_out, int out_size, void* d_ws, size_t ws_size,
                              hipStream_t stream) {
  const float* x    = (const float*)d_in[0];
  const float* Wqkv = (const float*)d_in[1];
  const float* bqkv = (const float*)d_in[2];
  const float* Wout = (const float*)d_in[3];
  const float* bout = (const float*)d_in[4];
  float* y = (float*)d_out;

  char* ws = (char*)d_ws;
  unsigned short* xb   = (unsigned short*)(ws);                 // 67,108,864 B
  float*          Wv   = (float*)(ws + 67108864);               //  1,048,576 B
  float*          Wsm  = (float*)(ws + 68157440);               //  1,048,576 B
  float*          beff = (float*)(ws + 69206016);               //      8,192 B
  unsigned short* Wt   = (unsigned short*)(ws + 69214208);      //  8,388,608 B  (total ~78 MB)

  k_cvt<<<16384, 256, 0, stream>>>(x, xb, 33554432L);
  k_wveff<<<1024, 256, 0, stream>>>(Wqkv, Wv);
  k_wsum<<<1024, 256, 0, stream>>>(Wout, Wsm);
  k_beff<<<8, 256, 0, stream>>>(bqkv, Wsm, bout, beff);
  k_weff<<<1024, 256, 0, stream>>>(Wv, Wsm, Wt);
  k_gemm<<<512, 512, 131072, stream>>>(xb, Wt, beff, y);
}

// Round 7
// 200.262 us; speedup vs baseline: 1.2910x; 1.0053x over previous
//
#include <hip/hip_runtime.h>
#include <hip/hip_bf16.h>
#include <cstdint>
#include <cstddef>

typedef short bf16x8 __attribute__((ext_vector_type(8)));
typedef float f32x4 __attribute__((ext_vector_type(4)));
typedef unsigned short u16x8 __attribute__((ext_vector_type(8)));

#define DEV __device__ __forceinline__

DEV void gload16(const void* g, void* l) {
  __builtin_amdgcn_global_load_lds((const __attribute__((address_space(1))) void*)g,
                                   (__attribute__((address_space(3))) void*)l,
                                   16, 0, 0);
}

DEV unsigned short f2bf(float f) {
  __hip_bfloat16 h = __float2bfloat16(f);
  return *reinterpret_cast<unsigned short*>(&h);
}

// ---------------- convert x fp32 -> bf16 (NT loads: x is read exactly once) ----------------
__global__ __launch_bounds__(256) void k_cvt(const float* __restrict__ in,
                                             unsigned short* __restrict__ out,
                                             long n) {
  long i = ((long)blockIdx.x * 256 + threadIdx.x) * 8;
  if (i >= n) return;
  const f32x4* p = (const f32x4*)(in + i);
  f32x4 a = __builtin_nontemporal_load(p);
  f32x4 b = __builtin_nontemporal_load(p + 1);
  u16x8 r;
  r[0] = f2bf(a[0]); r[1] = f2bf(a[1]); r[2] = f2bf(a[2]); r[3] = f2bf(a[3]);
  r[4] = f2bf(b[0]); r[5] = f2bf(b[1]); r[6] = f2bf(b[2]); r[7] = f2bf(b[3]);
  *(u16x8*)(out + i) = r;  // xb is re-read by k_gemm: keep cached
}

// ---------------- Wv_eff[k][d] = sum_h Wqkv[k][h][256+d]  (fp32) ----------------
__global__ __launch_bounds__(256) void k_wveff(const float* __restrict__ Wqkv,
                                               float* __restrict__ Wv) {
  int gid = blockIdx.x * 256 + threadIdx.x;  // 2048*128 = 262144
  int k = gid >> 7, d = gid & 127;
  const float* p = Wqkv + (size_t)k * 6144 + 256 + d;
  float s = 0.f;
#pragma unroll
  for (int h = 0; h < 16; ++h) s += __builtin_nontemporal_load(p + h * 384);
  Wv[gid] = s;  // Wv[k*128 + d]
}

// ---------------- Wsum[d][m] = sum_h Wout[h][d][m]  (fp32; NT: Wout read once) ----------------
__global__ __launch_bounds__(256) void k_wsum(const float* __restrict__ Wout,
                                              float* __restrict__ Ws) {
  int gid = blockIdx.x * 256 + threadIdx.x;  // 128*2048 = 262144
  int d = gid >> 11, m = gid & 2047;
  const float* p = Wout + (size_t)d * 2048 + m;
  float s = 0.f;
#pragma unroll
  for (int h = 0; h < 16; ++h) s += __builtin_nontemporal_load(p + h * 262144);
  Ws[gid] = s;  // Ws[d*2048 + m]
}

// ---------------- beff[m] = bout[m] + sum_d (sum_h bqkv[h][256+d]) * Ws[d][m] ----------------
__global__ __launch_bounds__(256) void k_beff(const float* __restrict__ bqkv,
                                              const float* __restrict__ Ws,
                                              const float* __restrict__ bout,
                                              float* __restrict__ be) {
  __shared__ float bv[128];
  int t = threadIdx.x;
  if (t < 128) {
    float s = 0.f;
#pragma unroll
    for (int h = 0; h < 16; ++h) s += bqkv[h * 384 + 256 + t];
    bv[t] = s;
  }
  __syncthreads();
  int m = blockIdx.x * 256 + t;  // grid 8 -> 2048
  float s = bout[m];
  for (int d = 0; d < 128; ++d) s = fmaf(bv[d], Ws[(size_t)d * 2048 + m], s);
  be[m] = s;
}

// ---------------- Weff_t[n][k] = sum_d Wv[k][d] * Ws[d][n]  (fp32 acc -> bf16) ----------------
__global__ __launch_bounds__(256) void k_weff(const float* __restrict__ Wv,
                                              const float* __restrict__ Ws,
                                              unsigned short* __restrict__ Wt) {
  __shared__ float wv_s[64][129];
  __shared__ float ws_s[128][64];
  const int t = threadIdx.x;
  const int tn = blockIdx.x & 31, tk = blockIdx.x >> 5;
#pragma unroll
  for (int it = 0; it < 32; ++it) {
    int idx = it * 256 + t;  // 8192
    int kk = idx >> 7, dd = idx & 127;
    wv_s[kk][dd] = Wv[(size_t)(tk * 64 + kk) * 128 + dd];
    int d2 = idx >> 6, nn = idx & 63;
    ws_s[d2][nn] = Ws[(size_t)d2 * 2048 + tn * 64 + nn];
  }
  __syncthreads();
  const int kk = t & 63, ng = t >> 6;
  float acc[16];
#pragma unroll
  for (int j = 0; j < 16; ++j) acc[j] = 0.f;
  for (int d = 0; d < 128; ++d) {
    float wv = wv_s[kk][d];
    const float* wsrow = &ws_s[d][ng * 16];
#pragma unroll
    for (int j = 0; j < 16; ++j) acc[j] = fmaf(wv, wsrow[j], acc[j]);
  }
#pragma unroll
  for (int j = 0; j < 16; ++j) {
    int n = tn * 64 + ng * 16 + j;
    Wt[(size_t)n * 2048 + tk * 64 + kk] = f2bf(acc[j]);
  }
}

// ---------------- main GEMM: 256x256 tile, BK=64, 8 waves ----------------
// Y[16384][2048] = A(bf16) * Wt[n][k]^T + bias.
// XCD-locality remap (r6: FETCH 270->98 MB): XCD x = bid&7 owns m-tiles 8x..8x+7.
// LDS 128 KiB dynamic, XOR-swizzled both-sides (rule #21).
// r7: intra-iter s_barriers REMOVED + A-fragment ds_reads software-pipelined one
// phase ahead (two named reg sets) — r6 counters showed LDS reads (~2312 cyc/iter)
// serialized against MFMA (~2484 cyc/iter) by the phase lockstep.
__global__ __launch_bounds__(512, 2) void k_gemm(const unsigned short* __restrict__ A,
                                                 const unsigned short* __restrict__ Bt,
                                                 const float* __restrict__ bias,
                                                 float* __restrict__ Y) {
  constexpr int KD = 2048;
  constexpr int NT = KD / 64;  // 32 K-tiles
  extern __shared__ char smem[];
  char* Asm = smem;              // 2 x 32768 B
  char* Bsm = smem + 65536;      // 2 x 32768 B
  const int t = threadIdx.x, lane = t & 63, w = t >> 6;
  const int wm = w >> 2, wn = w & 3;
  const int l15 = lane & 15, l4 = lane >> 4;
  const int bid = blockIdx.x;
  const int xcd = bid & 7;            // dispatch round-robins blocks over XCDs
  const int j = bid >> 3;             // per-XCD sequence 0..63
  const int rnd = j >> 5;             // co-resident round 0/1
  const int mt = xcd * 8 + rnd * 4 + ((j & 31) >> 3);
  const int ntile = j & 7;
  const int m0 = mt * 256, n0 = ntile * 256;

  // staging source (pre-swizzled): chunk c -> LDS rows c*64..c*64+63
  int srow[4], scol[4];
#pragma unroll
  for (int c = 0; c < 4; ++c) {
    srow[c] = (c * 512 + t) >> 3;
    scol[c] = ((t & 7) * 16) ^ ((srow[c] & 7) << 4);
  }
  const char* Ab = (const char*)A + (size_t)m0 * 4096;
  const char* Bb = (const char*)Bt + (size_t)n0 * 4096;

  f32x4 acc[8][4];
#pragma unroll
  for (int i = 0; i < 8; ++i)
#pragma unroll
    for (int j2 = 0; j2 < 4; ++j2)
#pragma unroll
      for (int r = 0; r < 4; ++r) acc[i][j2][r] = 0.f;

  // prologue: stage tile 0 into buf 0
#pragma unroll
  for (int c = 0; c < 4; ++c) {
    gload16(Ab + (size_t)srow[c] * 4096 + scol[c], Asm + c * 8192 + w * 1024);
    gload16(Bb + (size_t)srow[c] * 4096 + scol[c], Bsm + c * 8192 + w * 1024);
  }
  __syncthreads();

  // A-fragment load (phase ph -> reg set af); col swizzle per rule #21
#define LOAD_A(af, ph)                                                        \
  _Pragma("unroll") for (int jj = 0; jj < 2; ++jj)                            \
  _Pragma("unroll") for (int ks = 0; ks < 2; ++ks) {                          \
    int row = wm * 128 + ((ph) * 2 + jj) * 16 + l15;                          \
    int colb = (ks * 64 + l4 * 16) ^ ((row & 7) << 4);                        \
    af[jj][ks] = *(const bf16x8*)(Ar + row * 128 + colb);                     \
  }
#define MMA_PH(af, ph)                                                        \
  __builtin_amdgcn_s_setprio(1);                                              \
  _Pragma("unroll") for (int jj = 0; jj < 2; ++jj)                            \
  _Pragma("unroll") for (int ni = 0; ni < 4; ++ni)                            \
  _Pragma("unroll") for (int ks = 0; ks < 2; ++ks)                            \
    acc[(ph) * 2 + jj][ni] = __builtin_amdgcn_mfma_f32_16x16x32_bf16(         \
        af[jj][ks], bfr[ni][ks], acc[(ph) * 2 + jj][ni], 0, 0, 0);            \
  __builtin_amdgcn_s_setprio(0);

  int q = 0;
  for (int kt = 0; kt < NT; ++kt) {
    // issue next tile's staging into the other buffer (drained by iter-end syncthreads)
    if (kt + 1 < NT) {
      const size_t kb = (size_t)(kt + 1) * 128;
      char* Ad = Asm + (q ^ 1) * 32768;
      char* Bd = Bsm + (q ^ 1) * 32768;
#pragma unroll
      for (int c = 0; c < 4; ++c) {
        gload16(Ab + (size_t)srow[c] * 4096 + kb + scol[c], Ad + c * 8192 + w * 1024);
        gload16(Bb + (size_t)srow[c] * 4096 + kb + scol[c], Bd + c * 8192 + w * 1024);
      }
    }
    const char* Ar = Asm + q * 32768;
    const char* Br = Bsm + q * 32768;

    // B fragments (held all iter)
    bf16x8 bfr[4][2];
#pragma unroll
    for (int ni = 0; ni < 4; ++ni)
#pragma unroll
      for (int ks = 0; ks < 2; ++ks) {
        int row = wn * 64 + ni * 16 + l15;
        int colb = (ks * 64 + l4 * 16) ^ ((row & 7) << 4);
        bfr[ni][ks] = *(const bf16x8*)(Br + row * 128 + colb);
      }

    // software-pipelined phases: load ph+1's A frags before ph's MFMA cluster
    bf16x8 afA[2][2], afB[2][2];
    LOAD_A(afA, 0)
    LOAD_A(afB, 1)
    MMA_PH(afA, 0)
    LOAD_A(afA, 2)
    MMA_PH(afB, 1)
    LOAD_A(afB, 3)
    MMA_PH(afA, 2)
    MMA_PH(afB, 3)

    __syncthreads();  // drains vmcnt(0): next tile resident; all reads of buf q done
    q ^= 1;
  }
#undef LOAD_A
#undef MMA_PH

  // epilogue (plain stores; NT variant regressed in round 5)
#pragma unroll
  for (int ni = 0; ni < 4; ++ni) {
    const int n = n0 + wn * 64 + ni * 16 + l15;
    const float bv = bias[n];
#pragma unroll
    for (int mi = 0; mi < 8; ++mi) {
#pragma unroll
      for (int r = 0; r < 4; ++r) {
        int mg = m0 + wm * 128 + mi * 16 + l4 * 4 + r;
        Y[(size_t)mg * 2048 + n] = acc[mi][ni][r] + bv;
      }
    }
  }
}

extern "C" void kernel_launch(void* const* d_in, const int* in_sizes, int n_in,
                              void* d_out, int out_size, void* d_ws, size_t ws_size,
                              hipStream_t stream) {
  const float* x    = (const float*)d_in[0];
  const float* Wqkv = (const float*)d_in[1];
  const float* bqkv = (const float*)d_in[2];
  const float* Wout = (const float*)d_in[3];
  const float* bout = (const float*)d_in[4];
  float* y = (float*)d_out;

  char* ws = (char*)d_ws;
  unsigned short* xb   = (unsigned short*)(ws);                 // 67,108,864 B
  float*          Wv   = (float*)(ws + 67108864);               //  1,048,576 B
  float*          Wsm  = (float*)(ws + 68157440);               //  1,048,576 B
  float*          beff = (float*)(ws + 69206016);               //      8,192 B
  unsigned short* Wt   = (unsigned short*)(ws + 69214208);      //  8,388,608 B  (total ~78 MB)

  k_cvt<<<16384, 256, 0, stream>>>(x, xb, 33554432L);
  k_wveff<<<1024, 256, 0, stream>>>(Wqkv, Wv);
  k_wsum<<<1024, 256, 0, stream>>>(Wout, Wsm);
  k_beff<<<8, 256, 0, stream>>>(bqkv, Wsm, bout, beff);
  k_weff<<<1024, 256, 0, stream>>>(Wv, Wsm, Wt);
  k_gemm<<<512, 512, 131072, stream>>>(xb, Wt, beff, y);
}

// Round 8
// 198.091 us; speedup vs baseline: 1.3051x; 1.0110x over previous
//
#include <hip/hip_runtime.h>
#include <hip/hip_bf16.h>
#include <cstdint>
#include <cstddef>

typedef short bf16x8 __attribute__((ext_vector_type(8)));
typedef float f32x4 __attribute__((ext_vector_type(4)));
typedef unsigned short u16x8 __attribute__((ext_vector_type(8)));

#define DEV __device__ __forceinline__

DEV void gload16(const void* g, void* l) {
  __builtin_amdgcn_global_load_lds((const __attribute__((address_space(1))) void*)g,
                                   (__attribute__((address_space(3))) void*)l,
                                   16, 0, 0);
}

DEV unsigned short f2bf(float f) {
  __hip_bfloat16 h = __float2bfloat16(f);
  return *reinterpret_cast<unsigned short*>(&h);
}

// ---------------- convert x fp32 -> bf16 (NT loads: x is read exactly once) ----------------
__global__ __launch_bounds__(256) void k_cvt(const float* __restrict__ in,
                                             unsigned short* __restrict__ out,
                                             long n) {
  long i = ((long)blockIdx.x * 256 + threadIdx.x) * 8;
  if (i >= n) return;
  const f32x4* p = (const f32x4*)(in + i);
  f32x4 a = __builtin_nontemporal_load(p);
  f32x4 b = __builtin_nontemporal_load(p + 1);
  u16x8 r;
  r[0] = f2bf(a[0]); r[1] = f2bf(a[1]); r[2] = f2bf(a[2]); r[3] = f2bf(a[3]);
  r[4] = f2bf(b[0]); r[5] = f2bf(b[1]); r[6] = f2bf(b[2]); r[7] = f2bf(b[3]);
  *(u16x8*)(out + i) = r;  // xb is re-read by k_gemm: keep cached
}

// ---------------- Wv_eff[k][d] = sum_h Wqkv[k][h][256+d]  (fp32) ----------------
__global__ __launch_bounds__(256) void k_wveff(const float* __restrict__ Wqkv,
                                               float* __restrict__ Wv) {
  int gid = blockIdx.x * 256 + threadIdx.x;  // 2048*128 = 262144
  int k = gid >> 7, d = gid & 127;
  const float* p = Wqkv + (size_t)k * 6144 + 256 + d;
  float s = 0.f;
#pragma unroll
  for (int h = 0; h < 16; ++h) s += __builtin_nontemporal_load(p + h * 384);
  Wv[gid] = s;  // Wv[k*128 + d]
}

// ---------------- Wsum[d][m] = sum_h Wout[h][d][m]  (fp32; NT: Wout read once) ----------------
__global__ __launch_bounds__(256) void k_wsum(const float* __restrict__ Wout,
                                              float* __restrict__ Ws) {
  int gid = blockIdx.x * 256 + threadIdx.x;  // 128*2048 = 262144
  int d = gid >> 11, m = gid & 2047;
  const float* p = Wout + (size_t)d * 2048 + m;
  float s = 0.f;
#pragma unroll
  for (int h = 0; h < 16; ++h) s += __builtin_nontemporal_load(p + h * 262144);
  Ws[gid] = s;  // Ws[d*2048 + m]
}

// ---------------- beff[m] = bout[m] + sum_d (sum_h bqkv[h][256+d]) * Ws[d][m] ----------------
__global__ __launch_bounds__(256) void k_beff(const float* __restrict__ bqkv,
                                              const float* __restrict__ Ws,
                                              const float* __restrict__ bout,
                                              float* __restrict__ be) {
  __shared__ float bv[128];
  int t = threadIdx.x;
  if (t < 128) {
    float s = 0.f;
#pragma unroll
    for (int h = 0; h < 16; ++h) s += bqkv[h * 384 + 256 + t];
    bv[t] = s;
  }
  __syncthreads();
  int m = blockIdx.x * 256 + t;  // grid 8 -> 2048
  float s = bout[m];
  for (int d = 0; d < 128; ++d) s = fmaf(bv[d], Ws[(size_t)d * 2048 + m], s);
  be[m] = s;
}

// ---------------- Weff_t[n][k] = sum_d Wv[k][d] * Ws[d][n]  (fp32 acc -> bf16) ----------------
__global__ __launch_bounds__(256) void k_weff(const float* __restrict__ Wv,
                                              const float* __restrict__ Ws,
                                              unsigned short* __restrict__ Wt) {
  __shared__ float wv_s[64][129];
  __shared__ float ws_s[128][64];
  const int t = threadIdx.x;
  const int tn = blockIdx.x & 31, tk = blockIdx.x >> 5;
#pragma unroll
  for (int it = 0; it < 32; ++it) {
    int idx = it * 256 + t;  // 8192
    int kk = idx >> 7, dd = idx & 127;
    wv_s[kk][dd] = Wv[(size_t)(tk * 64 + kk) * 128 + dd];
    int d2 = idx >> 6, nn = idx & 63;
    ws_s[d2][nn] = Ws[(size_t)d2 * 2048 + tn * 64 + nn];
  }
  __syncthreads();
  const int kk = t & 63, ng = t >> 6;
  float acc[16];
#pragma unroll
  for (int j = 0; j < 16; ++j) acc[j] = 0.f;
  for (int d = 0; d < 128; ++d) {
    float wv = wv_s[kk][d];
    const float* wsrow = &ws_s[d][ng * 16];
#pragma unroll
    for (int j = 0; j < 16; ++j) acc[j] = fmaf(wv, wsrow[j], acc[j]);
  }
#pragma unroll
  for (int j = 0; j < 16; ++j) {
    int n = tn * 64 + ng * 16 + j;
    Wt[(size_t)n * 2048 + tk * 64 + kk] = f2bf(acc[j]);
  }
}

// stage one chunk (A-quadrant s rows {s*32..+31}∪{128+s*32..+31}, B rows s*64..s*64+63)
// of K-tile kt2 into buf qd. 2 global_load_lds per thread; pre-swizzled source (rule #21).
DEV void stage_chunk(const char* Ab, const char* Bb, char* Asm, char* Bsm,
                     int t, int w, int kt2, int s, int qd) {
  const int rl = t >> 3;        // 0..63
  const int rl0 = w * 8;        // wave base row_local
  // A
  const int arow  = s * 32 + (rl  & 31) + ((rl  >> 5) << 7);
  const int arow0 = s * 32 + (rl0 & 31) + ((rl0 >> 5) << 7);
  const int sca = ((t & 7) * 16) ^ ((arow & 7) << 4);
  gload16(Ab + (size_t)arow * 4096 + (size_t)kt2 * 128 + sca,
          Asm + qd * 32768 + arow0 * 128);
  // B
  const int brow = s * 64 + rl;
  const int scb = ((t & 7) * 16) ^ ((brow & 7) << 4);
  gload16(Bb + (size_t)brow * 4096 + (size_t)kt2 * 128 + scb,
          Bsm + qd * 32768 + (s * 64 + rl0) * 128);
}

// ---------------- main GEMM: 256x256 tile, BK=64, 8 waves, 8-phase counted-vmcnt ----------------
// Y[16384][2048] = A(bf16) * Wt[n][k]^T + bias.
// XCD-locality remap (r6: FETCH 270->98 MB). LDS 128 KiB, XOR-swizzle both-sides (T2, r4: conflicts=0).
// r8 (T3+T4): per K-tile 4 phases {ds_read ∥ 2 stage-issues -> s_barrier -> lgkmcnt(0) ->
// setprio(1) 16 MFMA setprio(0) -> s_barrier}. Staging of tile t+2 chunk p issued at phase p+1
// (region last read at phase p). vmcnt(6) at each K-tile's LAST phase (pre-barrier): 6 = 2 loads x
// 3 chunks in flight; the closing barrier orders it before tile t+1's ds_reads across all waves.
// No vmcnt(0) drain in the main loop (m218: counted-vs-drain0 = +38%).
__global__ __launch_bounds__(512, 2) void k_gemm(const unsigned short* __restrict__ A,
                                                 const unsigned short* __restrict__ Bt,
                                                 const float* __restrict__ bias,
                                                 float* __restrict__ Y) {
  extern __shared__ char smem[];
  char* Asm = smem;              // 2 x 32768 B (A: 256 rows x 128 B)
  char* Bsm = smem + 65536;      // 2 x 32768 B
  const int t = threadIdx.x, lane = t & 63, w = t >> 6;
  const int wm = w >> 2, wn = w & 3;
  const int l15 = lane & 15, l4 = lane >> 4;
  const int bid = blockIdx.x;
  const int xcd = bid & 7;            // dispatch round-robins blocks over XCDs
  const int j = bid >> 3;             // per-XCD sequence 0..63
  const int rnd = j >> 5;             // co-resident round 0/1
  const int mt = xcd * 8 + rnd * 4 + ((j & 31) >> 3);
  const int ntile = j & 7;
  const int m0 = mt * 256, n0 = ntile * 256;

  const char* Ab = (const char*)A + (size_t)m0 * 4096;
  const char* Bb = (const char*)Bt + (size_t)n0 * 4096;

  f32x4 acc[8][4];
#pragma unroll
  for (int i = 0; i < 8; ++i)
#pragma unroll
    for (int j2 = 0; j2 < 4; ++j2)
#pragma unroll
      for (int r = 0; r < 4; ++r) acc[i][j2][r] = 0.f;

#define VMCNT(n) asm volatile("s_waitcnt vmcnt(" #n ")" ::: "memory")
#define LGKM0() asm volatile("s_waitcnt lgkmcnt(0)" ::: "memory")
#define BAR() __builtin_amdgcn_s_barrier()
#define SC(k2, s, qd) stage_chunk(Ab, Bb, Asm, Bsm, t, w, (k2), (s), (qd))
#define NOPS() ((void)0)

#define LOAD_B()                                                              \
  _Pragma("unroll") for (int ni = 0; ni < 4; ++ni)                            \
  _Pragma("unroll") for (int ks = 0; ks < 2; ++ks) {                          \
    int row = wn * 64 + ni * 16 + l15;                                        \
    int colb = (ks * 64 + l4 * 16) ^ ((row & 7) << 4);                        \
    bfr[ni][ks] = *(const bf16x8*)(Br + row * 128 + colb);                    \
  }
#define LOAD_A(p)                                                             \
  _Pragma("unroll") for (int jj = 0; jj < 2; ++jj)                            \
  _Pragma("unroll") for (int ks = 0; ks < 2; ++ks) {                          \
    int row = wm * 128 + ((p) * 2 + jj) * 16 + l15;                           \
    int colb = (ks * 64 + l4 * 16) ^ ((row & 7) << 4);                        \
    af[jj][ks] = *(const bf16x8*)(Ar + row * 128 + colb);                     \
  }
#define MMA(p)                                                                \
  __builtin_amdgcn_s_setprio(1);                                              \
  _Pragma("unroll") for (int jj = 0; jj < 2; ++jj)                            \
  _Pragma("unroll") for (int ni = 0; ni < 4; ++ni)                            \
  _Pragma("unroll") for (int ks = 0; ks < 2; ++ks)                            \
    acc[(p) * 2 + jj][ni] = __builtin_amdgcn_mfma_f32_16x16x32_bf16(          \
        af[jj][ks], bfr[ni][ks], acc[(p) * 2 + jj][ni], 0, 0, 0);             \
  __builtin_amdgcn_s_setprio(0);

#define KTILE(q, S0, S1, S2, S3, VML)                                         \
  do {                                                                        \
    const char* Ar = Asm + (q) * 32768;                                       \
    const char* Br = Bsm + (q) * 32768;                                       \
    bf16x8 bfr[4][2], af[2][2];                                               \
    LOAD_B(); LOAD_A(0); S0;      BAR(); LGKM0(); MMA(0); BAR();              \
    LOAD_A(1); S1;                BAR(); LGKM0(); MMA(1); BAR();              \
    LOAD_A(2); S2;                BAR(); LGKM0(); MMA(2); BAR();              \
    LOAD_A(3); S3; VML;           BAR(); LGKM0(); MMA(3); BAR();              \
  } while (0)

  // prologue: tile0 fully (8 loads), tile1 chunks 0-2 (6 loads)
#pragma unroll
  for (int s = 0; s < 4; ++s) SC(0, s, 0);
#pragma unroll
  for (int s = 0; s < 3; ++s) SC(1, s, 1);
  VMCNT(6);   // own tile-0 loads landed (tile-1's 6 may remain in flight)
  BAR();      // all waves confirmed -> tile 0 fully resident

  int kt = 0;
#pragma unroll 1
  for (int it = 0; it < 15; ++it, kt += 2) {
    KTILE(0, SC(kt + 1, 3, 1), SC(kt + 2, 0, 0), SC(kt + 2, 1, 0), SC(kt + 2, 2, 0), VMCNT(6));
    KTILE(1, SC(kt + 2, 3, 0), SC(kt + 3, 0, 1), SC(kt + 3, 1, 1), SC(kt + 3, 2, 1), VMCNT(6));
  }
  // peeled final pair: kt == 30
  KTILE(0, SC(31, 3, 1), NOPS(), NOPS(), NOPS(), VMCNT(0));
  KTILE(1, NOPS(), NOPS(), NOPS(), NOPS(), NOPS());

#undef KTILE
#undef MMA
#undef LOAD_A
#undef LOAD_B
#undef SC
#undef NOPS
#undef VMCNT
#undef LGKM0
#undef BAR

  // epilogue
#pragma unroll
  for (int ni = 0; ni < 4; ++ni) {
    const int n = n0 + wn * 64 + ni * 16 + l15;
    const float bv = bias[n];
#pragma unroll
    for (int mi = 0; mi < 8; ++mi) {
#pragma unroll
      for (int r = 0; r < 4; ++r) {
        int mg = m0 + wm * 128 + mi * 16 + l4 * 4 + r;
        Y[(size_t)mg * 2048 + n] = acc[mi][ni][r] + bv;
      }
    }
  }
}

extern "C" void kernel_launch(void* const* d_in, const int* in_sizes, int n_in,
                              void* d_out, int out_size, void* d_ws, size_t ws_size,
                              hipStream_t stream) {
  const float* x    = (const float*)d_in[0];
  const float* Wqkv = (const float*)d_in[1];
  const float* bqkv = (const float*)d_in[2];
  const float* Wout = (const float*)d_in[3];
  const float* bout = (const float*)d_in[4];
  float* y = (float*)d_out;

  char* ws = (char*)d_ws;
  unsigned short* xb   = (unsigned short*)(ws);                 // 67,108,864 B
  float*          Wv   = (float*)(ws + 67108864);               //  1,048,576 B
  float*          Wsm  = (float*)(ws + 68157440);               //  1,048,576 B
  float*          beff = (float*)(ws + 69206016);               //      8,192 B
  unsigned short* Wt   = (unsigned short*)(ws + 69214208);      //  8,388,608 B  (total ~78 MB)

  k_cvt<<<16384, 256, 0, stream>>>(x, xb, 33554432L);
  k_wveff<<<1024, 256, 0, stream>>>(Wqkv, Wv);
  k_wsum<<<1024, 256, 0, stream>>>(Wout, Wsm);
  k_beff<<<8, 256, 0, stream>>>(bqkv, Wsm, bout, beff);
  k_weff<<<1024, 256, 0, stream>>>(Wv, Wsm, Wt);
  k_gemm<<<512, 512, 131072, stream>>>(xb, Wt, beff, y);
}

// Round 9
// 110.371 us; speedup vs baseline: 2.3424x; 1.7948x over previous
//
#include <hip/hip_runtime.h>
#include <hip/hip_bf16.h>
#include <cstdint>
#include <cstddef>

typedef short bf16x8 __attribute__((ext_vector_type(8)));
typedef float f32x4 __attribute__((ext_vector_type(4)));
typedef unsigned short u16x8 __attribute__((ext_vector_type(8)));

#define DEV __device__ __forceinline__

DEV void gload16(const void* g, void* l) {
  __builtin_amdgcn_global_load_lds((const __attribute__((address_space(1))) void*)g,
                                   (__attribute__((address_space(3))) void*)l,
                                   16, 0, 0);
}

DEV unsigned short f2bf(float f) {
  __hip_bfloat16 h = __float2bfloat16(f);
  return *reinterpret_cast<unsigned short*>(&h);
}

DEV float b2f(unsigned short u) {
  union { float f; unsigned int i; } v;
  v.i = ((unsigned int)u) << 16;
  return v.f;
}

// ---- Wvt[d][k] bf16 = sum_h Wqkv[k][h][256+d]  (rank-128 left factor, transposed) ----
__global__ __launch_bounds__(256) void k_wv(const float* __restrict__ Wqkv,
                                            unsigned short* __restrict__ Wvt) {
  int gid = blockIdx.x * 256 + threadIdx.x;  // 2048 k x 128 d
  int k = gid >> 7, d = gid & 127;
  const float* p = Wqkv + (size_t)k * 6144 + 256 + d;
  float s = 0.f;
#pragma unroll
  for (int h = 0; h < 16; ++h) s += __builtin_nontemporal_load(p + h * 384);
  Wvt[(size_t)d * 2048 + k] = f2bf(s);  // scattered 2B; 0.5 MB total, L2-absorbed
}

// ---- Wst[m][d] bf16 = sum_h Wout[h][d][m]  (right factor, transposed) ----
__global__ __launch_bounds__(256) void k_ws(const float* __restrict__ Wout,
                                            unsigned short* __restrict__ Wst) {
  int gid = blockIdx.x * 256 + threadIdx.x;  // 128 d x 2048 m
  int d = gid >> 11, m = gid & 2047;
  const float* p = Wout + (size_t)d * 2048 + m;
  float s = 0.f;
#pragma unroll
  for (int h = 0; h < 16; ++h) s += __builtin_nontemporal_load(p + h * 262144);
  Wst[(size_t)m * 128 + d] = f2bf(s);
}

// ---- beff[m] = bout[m] + sum_d (sum_h bqkv[h][256+d]) * Ws[d][m] ----
__global__ __launch_bounds__(256) void k_beff(const float* __restrict__ bqkv,
                                              const unsigned short* __restrict__ Wst,
                                              const float* __restrict__ bout,
                                              float* __restrict__ be) {
  __shared__ float bv[128];
  int t = threadIdx.x;
  if (t < 128) {
    float s = 0.f;
#pragma unroll
    for (int h = 0; h < 16; ++h) s += bqkv[h * 384 + 256 + t];
    bv[t] = s;
  }
  __syncthreads();
  int m = blockIdx.x * 256 + t;  // grid 8
  float s = bout[m];
  const unsigned short* wr = Wst + (size_t)m * 128;
  for (int d = 0; d < 128; ++d) s = fmaf(bv[d], b2f(wr[d]), s);
  be[m] = s;
}

// ---- GEMM1: T[16384][128] bf16 = X(fp32, cvt in-reg) * Wvt^T ----
// 512 blocks x 256 thr (4 waves 2m x 2n), m-tile 32, BK=64, B double-buffered in LDS
// (gload16 + (row&7)<<4 swizzle both-sides), A reg-double-buffered NT fp32 loads.
__global__ __launch_bounds__(256, 2) void k_gemm1(const float* __restrict__ X,
                                                  const unsigned short* __restrict__ Wvt,
                                                  unsigned short* __restrict__ T) {
  __shared__ char bs[2][16384];
  const int t = threadIdx.x, lane = t & 63, w = t >> 6;
  const int wm = w >> 1, wn = w & 1;
  const int l15 = lane & 15, l4 = lane >> 4;
  const int m0 = blockIdx.x * 32;

  int srow[4], scol[4];
#pragma unroll
  for (int c = 0; c < 4; ++c) {
    srow[c] = c * 32 + (t >> 3);
    scol[c] = ((t & 7) * 16) ^ ((srow[c] & 7) << 4);
  }
  const float* xrow = X + (size_t)(m0 + wm * 16 + l15) * 2048;

  f32x4 acc[4];
#pragma unroll
  for (int ni = 0; ni < 4; ++ni)
#pragma unroll
    for (int r = 0; r < 4; ++r) acc[ni][r] = 0.f;

#define STAGE1(kt2, q)                                                         \
  _Pragma("unroll") for (int c = 0; c < 4; ++c)                                \
      gload16((const char*)Wvt + (size_t)srow[c] * 4096 + (kt2) * 128 + scol[c],\
              bs[q] + c * 4096 + w * 1024);
#define ALOAD(ra, kt2)                                                         \
  _Pragma("unroll") for (int i = 0; i < 4; ++i)                                \
      ra[i] = __builtin_nontemporal_load(                                      \
          (const f32x4*)(xrow + (kt2) * 64 + (i >> 1) * 32 + l4 * 8 + (i & 1) * 4));
#define COMP1(q, ra)                                                           \
  do {                                                                         \
    bf16x8 af[2];                                                              \
    _Pragma("unroll") for (int ks = 0; ks < 2; ++ks) {                         \
      u16x8 u;                                                                 \
      _Pragma("unroll") for (int jj = 0; jj < 4; ++jj) {                       \
        u[jj] = f2bf(ra[ks * 2][jj]); u[jj + 4] = f2bf(ra[ks * 2 + 1][jj]);    \
      }                                                                        \
      af[ks] = (bf16x8)u;                                                      \
    }                                                                          \
    _Pragma("unroll") for (int ni = 0; ni < 4; ++ni)                           \
    _Pragma("unroll") for (int ks = 0; ks < 2; ++ks) {                         \
      int row = wn * 64 + ni * 16 + l15;                                       \
      int byt = (ks * 64 + l4 * 16) ^ ((row & 7) << 4);                        \
      bf16x8 bf = *(const bf16x8*)(bs[q] + row * 128 + byt);                   \
      acc[ni] = __builtin_amdgcn_mfma_f32_16x16x32_bf16(af[ks], bf, acc[ni], 0, 0, 0); \
    }                                                                          \
  } while (0)

  f32x4 raA[4], raB[4];
  STAGE1(0, 0) ALOAD(raA, 0)
  __syncthreads();
#pragma unroll 1
  for (int kt = 0; kt < 32; kt += 2) {
    STAGE1(kt + 1, 1) ALOAD(raB, kt + 1)
    COMP1(0, raA);
    __syncthreads();
    if (kt + 2 < 32) { STAGE1(kt + 2, 0) ALOAD(raA, kt + 2) }
    COMP1(1, raB);
    __syncthreads();
  }
#undef STAGE1
#undef ALOAD
#undef COMP1

#pragma unroll
  for (int ni = 0; ni < 4; ++ni)
#pragma unroll
    for (int r = 0; r < 4; ++r) {
      int row = m0 + wm * 16 + l4 * 4 + r;
      int col = wn * 64 + ni * 16 + l15;
      T[(size_t)row * 128 + col] = f2bf(acc[ni][r]);
    }
}

// ---- GEMM2: Y[16384][2048] fp32 = T * Wst^T + beff.  K=128 single sweep ----
// grid (256 m, 8 n) x 256 thr (4 waves x 16 rows x 256 cols). B-tile 64 KB one-shot stage.
__global__ __launch_bounds__(256, 2) void k_gemm2(const unsigned short* __restrict__ Tm,
                                                  const unsigned short* __restrict__ Wst,
                                                  const float* __restrict__ be,
                                                  float* __restrict__ Y) {
  __shared__ char bs[65536];
  const int t = threadIdx.x, lane = t & 63, w = t >> 6;
  const int l15 = lane & 15, l4 = lane >> 4;
  const int m0 = blockIdx.x * 64, n0 = blockIdx.y * 256;

#pragma unroll
  for (int c = 0; c < 16; ++c) {
    int row = c * 16 + (t >> 4);
    int sc = ((t & 15) * 16) ^ ((row & 7) << 4);
    gload16((const char*)Wst + (size_t)(n0 + row) * 256 + sc, bs + c * 4096 + w * 1024);
  }
  const unsigned short* trow = Tm + (size_t)(m0 + w * 16 + l15) * 128;
  bf16x8 afr[4];
#pragma unroll
  for (int kq = 0; kq < 4; ++kq) afr[kq] = *(const bf16x8*)(trow + kq * 32 + l4 * 8);
  __syncthreads();

  f32x4 acc[16];
#pragma unroll
  for (int ni = 0; ni < 16; ++ni)
#pragma unroll
    for (int r = 0; r < 4; ++r) acc[ni][r] = 0.f;

#pragma unroll
  for (int ni = 0; ni < 16; ++ni) {
    int row = ni * 16 + l15;
#pragma unroll
    for (int kq = 0; kq < 4; ++kq) {
      int byt = (kq * 64 + l4 * 16) ^ ((row & 7) << 4);
      bf16x8 bf = *(const bf16x8*)(bs + row * 256 + byt);
      acc[ni] = __builtin_amdgcn_mfma_f32_16x16x32_bf16(afr[kq], bf, acc[ni], 0, 0, 0);
    }
  }

#pragma unroll
  for (int ni = 0; ni < 16; ++ni) {
    int n = n0 + ni * 16 + l15;
    float bv = be[n];
#pragma unroll
    for (int r = 0; r < 4; ++r) {
      int row = m0 + w * 16 + l4 * 4 + r;
      Y[(size_t)row * 2048 + n] = acc[ni][r] + bv;
    }
  }
}

extern "C" void kernel_launch(void* const* d_in, const int* in_sizes, int n_in,
                              void* d_out, int out_size, void* d_ws, size_t ws_size,
                              hipStream_t stream) {
  const float* x    = (const float*)d_in[0];
  const float* Wqkv = (const float*)d_in[1];
  const float* bqkv = (const float*)d_in[2];
  const float* Wout = (const float*)d_in[3];
  const float* bout = (const float*)d_in[4];
  float* y = (float*)d_out;

  char* ws = (char*)d_ws;
  unsigned short* Wvt  = (unsigned short*)(ws);             //   524,288 B  [128][2048] bf16
  unsigned short* Wst  = (unsigned short*)(ws + 524288);    //   524,288 B  [2048][128] bf16
  float*          beff = (float*)(ws + 1048576);            //     8,192 B
  unsigned short* T    = (unsigned short*)(ws + 1056768);   // 4,194,304 B  [16384][128] bf16

  k_wv<<<1024, 256, 0, stream>>>(Wqkv, Wvt);
  k_ws<<<1024, 256, 0, stream>>>(Wout, Wst);
  k_beff<<<8, 256, 0, stream>>>(bqkv, Wst, bout, beff);
  k_gemm1<<<512, 256, 0, stream>>>(x, Wvt, T);
  k_gemm2<<<dim3(256, 8), 256, 0, stream>>>(T, Wst, beff, y);
}